// Round 5
// baseline (2723.874 us; speedup 1.0000x reference)
//
#include <hip/hip_runtime.h>

typedef __attribute__((ext_vector_type(8))) short bf16x8;
typedef __attribute__((ext_vector_type(4))) unsigned int u32x4;

#define NPTS 50000
#define NB 4

static __device__ __forceinline__ unsigned short f2bf(float f) {
  union { float f; unsigned u; } v; v.f = f;
  unsigned r = v.u + 0x7fffu + ((v.u >> 16) & 1u);
  return (unsigned short)(r >> 16);
}

static __device__ __forceinline__ float bf2f(unsigned short h) {
  union { unsigned u; float f; } v; v.u = ((unsigned)h) << 16; return v.f;
}

// Transpose + fp32->bf16 convert: latT[b][c][g] = latents[b][g*512 + c]
__global__ void lat_transpose_kernel(const float* __restrict__ lat,
                                     unsigned short* __restrict__ latT) {
  __shared__ float tile[32][33];
  int b = blockIdx.z;
  int gt = blockIdx.x * 32, ct = blockIdx.y * 32;
  const float* src = lat + (size_t)b * 512 * 512;
  unsigned short* dst = latT + (size_t)b * 512 * 512;
#pragma unroll
  for (int i = 0; i < 4; i++) {
    int g = gt + threadIdx.y + 8 * i;
    tile[threadIdx.y + 8 * i][threadIdx.x] = src[(size_t)g * 512 + ct + threadIdx.x];
  }
  __syncthreads();
#pragma unroll
  for (int i = 0; i < 4; i++) {
    int c = ct + threadIdx.y + 8 * i;
    dst[(size_t)c * 512 + gt + threadIdx.x] = f2bf(tile[threadIdx.x][threadIdx.y + 8 * i]);
  }
}

// DIAGNOSTIC: phase 1 (RBF data -> LDS bf16 granules) and the latT transpose
// are byte-identical to rounds 1/4. Phase 2 is a trivially-correct VALU dot
// product: thread t owns output column c=t for all 64 points of the tile.
// PASS => data-prep + output indexing validated; bug was MFMA usage.
// FAIL => data-prep (phase 1 / transpose) is wrong.
__global__ __launch_bounds__(512)
void rbf_mm_valu_kernel(const float* __restrict__ points,
                        const float* __restrict__ epsilon,
                        const unsigned short* __restrict__ latT,
                        float* __restrict__ out) {
  __shared__ __align__(16) unsigned int sdat[64 * 64 * 4]; // 64 KiB

  const int t = threadIdx.x;
  const int w = t >> 6;
  const int l = t & 63;
  const int b = blockIdx.y;
  const int n0 = blockIdx.x * 64;

  // ---- Phase 1: data[row=l][g] for all 512 g (8 granules per thread) ----
  int np = n0 + l; if (np > NPTS - 1) np = NPTS - 1;
  const float* pp = points + ((size_t)b * NPTS + np) * 3;
  const float px = pp[0], py = pp[1], pz = pp[2];
  const float p2 = px * px + py * py + pz * pz;
  const float step = 2.0f / 7.0f;

#pragma unroll
  for (int m = 0; m < 8; m++) {
    const int q = w + 8 * m;      // k-granule index; g in [q*8, q*8+8)
    unsigned pk[4];
#pragma unroll
    for (int jj = 0; jj < 4; jj++) {
      unsigned short h[2];
#pragma unroll
      for (int j2 = 0; j2 < 2; j2++) {
        const int g = q * 8 + jj * 2 + j2;
        const float cx = -1.f + step * (float)(g >> 6);
        const float cy = -1.f + step * (float)((g >> 3) & 7);
        const float cz = -1.f + step * (float)(g & 7);
        const float g2 = cx * cx + cy * cy + cz * cz;
        float d2 = p2 + g2 - 2.f * (px * cx + py * cy + pz * cz);
        d2 = fmaxf(d2, 0.f);
        const float e = epsilon[g];
        h[j2] = f2bf(__expf(-e * e * d2));
      }
      pk[jj] = (unsigned)h[0] | ((unsigned)h[1] << 16);
    }
    u32x4 v = {pk[0], pk[1], pk[2], pk[3]};
    reinterpret_cast<u32x4*>(sdat)[q * 64 + l] = v;
  }

  __syncthreads();

  // ---- Phase 2 (VALU, reference-faithful): out[pt][c] = sum_g data*latT ----
  const int c = t;  // 0..511
  const unsigned short* Bp = latT + (size_t)b * 512 * 512 + (size_t)c * 512;
  const bf16x8* A = reinterpret_cast<const bf16x8*>(sdat);

  float acc[64];
#pragma unroll
  for (int pt = 0; pt < 64; pt++) acc[pt] = 0.f;

#pragma unroll 1
  for (int kq = 0; kq < 64; kq++) {
    const bf16x8 lv = *reinterpret_cast<const bf16x8*>(Bp + kq * 8);
    float lf[8];
#pragma unroll
    for (int j = 0; j < 8; j++) lf[j] = bf2f((unsigned short)lv[j]);
#pragma unroll
    for (int pt = 0; pt < 64; pt++) {
      const bf16x8 dv = A[kq * 64 + pt];   // wave-uniform addr -> broadcast
#pragma unroll
      for (int j = 0; j < 8; j++)
        acc[pt] += bf2f((unsigned short)dv[j]) * lf[j];
    }
  }

  // ---- Write: row-major, coalesced across threads (consecutive c) ----
  float* op = out + (size_t)b * NPTS * 512;
#pragma unroll 1
  for (int pt = 0; pt < 64; pt++) {
    const int n_pt = n0 + pt;
    if (n_pt < NPTS) op[(size_t)n_pt * 512 + c] = acc[pt];
  }
}

extern "C" void kernel_launch(void* const* d_in, const int* in_sizes, int n_in,
                              void* d_out, int out_size, void* d_ws, size_t ws_size,
                              hipStream_t stream) {
  const float* points  = (const float*)d_in[0];   // [4, 50000, 3] f32
  const float* latents = (const float*)d_in[1];   // [4, 512, 8,8,8] f32
  const float* epsilon = (const float*)d_in[2];   // [512] f32
  float* out = (float*)d_out;                     // [4, 50000, 512] f32
  unsigned short* latT = (unsigned short*)d_ws;   // [4][512 c][512 g] bf16 (2 MiB)

  dim3 tb(32, 8, 1), tg(16, 16, 4);
  lat_transpose_kernel<<<tg, tb, 0, stream>>>(latents, latT);

  dim3 mg((NPTS + 63) / 64, NB, 1);
  rbf_mm_valu_kernel<<<mg, dim3(512, 1, 1), 0, stream>>>(points, epsilon, latT, out);
}